// Round 11
// baseline (193.977 us; speedup 1.0000x reference)
//
#include <hip/hip_runtime.h>
#include <hip/hip_bf16.h>

#define NN 50000
#define NE 400000
#define NT 3125   // NN/16 row tiles

typedef unsigned short u16;
typedef short short8 __attribute__((ext_vector_type(8)));
typedef float f32x4 __attribute__((ext_vector_type(4)));

__device__ __forceinline__ float geluf(float x){ return 0.5f*x*(1.0f+erff(x*0.70710678118654752440f)); }
__device__ __forceinline__ u16 f2bfb(float f){
  union { __hip_bfloat16 h; u16 u; } cv; cv.h = __float2bfloat16(f); return cv.u;
}
__device__ __forceinline__ float bfb2f(u16 u){ return __uint_as_float(((unsigned)u)<<16); }

// ---- K1 (MFMA, operand-swapped): Hb/GHb tiles; lane holds out[row=l&15][col=nb*16+kgrp*4+r]
__global__ __launch_bounds__(512) void k_ff1(const float* __restrict__ X,
    const float* __restrict__ W1, const float* __restrict__ b1,
    u16* __restrict__ Hb, u16* __restrict__ GHb)
{
  extern __shared__ u16 wls[];            // [128 c][136 k] bf16 padded
  const int LDW = 136;
  for (int idx4 = threadIdx.x*4; idx4 < 128*128; idx4 += 512*4){
    int c = idx4 >> 7, k = idx4 & 127;
    float4 v = *(const float4*)(W1 + (size_t)c*128 + k);
    ushort2 p0, p1;
    p0.x = f2bfb(v.x); p0.y = f2bfb(v.y);
    p1.x = f2bfb(v.z); p1.y = f2bfb(v.w);
    *(ushort2*)&wls[c*LDW + k]     = p0;
    *(ushort2*)&wls[c*LDW + k + 2] = p1;
  }
  __syncthreads();
  const int lane = threadIdx.x & 63;
  const int wave = threadIdx.x >> 6;
  const int lrow = lane & 15;
  const int kgrp = lane >> 4;
  float4 b1v[8];
  #pragma unroll
  for (int nb = 0; nb < 8; nb++) b1v[nb] = *(const float4*)(b1 + nb*16 + kgrp*4);
  for (int tile = blockIdx.x*8 + wave; tile < NT; tile += gridDim.x*8){
    const float* xr = X + (size_t)(tile*16 + lrow)*128 + kgrp*8;
    f32x4 acc[8];
    #pragma unroll
    for (int nb = 0; nb < 8; nb++) acc[nb] = (f32x4){0.f,0.f,0.f,0.f};
    #pragma unroll
    for (int kk = 0; kk < 4; kk++){
      float4 xa = *(const float4*)(xr + kk*32);
      float4 xb = *(const float4*)(xr + kk*32 + 4);
      union { short8 v; u16 u[8]; } af;
      af.u[0]=f2bfb(xa.x); af.u[1]=f2bfb(xa.y); af.u[2]=f2bfb(xa.z); af.u[3]=f2bfb(xa.w);
      af.u[4]=f2bfb(xb.x); af.u[5]=f2bfb(xb.y); af.u[6]=f2bfb(xb.z); af.u[7]=f2bfb(xb.w);
      #pragma unroll
      for (int nb = 0; nb < 8; nb++){
        short8 bf = *(const short8*)&wls[(nb*16 + lrow)*LDW + kk*32 + kgrp*8];
        acc[nb] = __builtin_amdgcn_mfma_f32_16x16x32_bf16(bf, af.v, acc[nb], 0, 0, 0);
      }
    }
    const size_t rb = (size_t)(tile*16 + lrow)*128 + kgrp*4;
    #pragma unroll
    for (int nb = 0; nb < 8; nb++){
      ushort4 hp, gp;
      #pragma unroll
      for (int r = 0; r < 4; r++){
        float h = geluf(acc[nb][r] + b1v[nb][r]);
        ((u16*)&hp)[r] = f2bfb(h);
        ((u16*)&gp)[r] = f2bfb(geluf(h));
      }
      *(ushort4*)(Hb  + rb + nb*16) = hp;
      *(ushort4*)(GHb + rb + nb*16) = gp;
    }
  }
}

// ---------------- sort edges by dst: hist -> scan -> fill(src) ----------------
__global__ void k_hist(const int* __restrict__ dst, int* __restrict__ deg){
  int e = blockIdx.x*256 + threadIdx.x;
  if (e < NE) atomicAdd(&deg[dst[e]], 1);
}

__global__ __launch_bounds__(1024) void k_scan(const int* __restrict__ deg, int* __restrict__ offs){
  __shared__ int wsum[16];
  __shared__ int sbase_s;
  const int tid = threadIdx.x, lane = tid & 63, wave = tid >> 6;
  if (tid == 0) sbase_s = 0;
  __syncthreads();
  for (int base = 0; base < NN; base += 4096){
    int i0 = base + tid*4;
    int v0=0,v1=0,v2=0,v3=0;
    if (i0+3 < NN){ int4 v = *(const int4*)(deg+i0); v0=v.x;v1=v.y;v2=v.z;v3=v.w; }
    else {
      if (i0   < NN) v0 = deg[i0];
      if (i0+1 < NN) v1 = deg[i0+1];
      if (i0+2 < NN) v2 = deg[i0+2];
    }
    int own = v0+v1+v2+v3;
    int inc = own;
    #pragma unroll
    for (int s=1;s<64;s<<=1){ int t = __shfl_up(inc, s, 64); if (lane >= s) inc += t; }
    if (lane == 63) wsum[wave] = inc;
    __syncthreads();
    if (wave == 0 && lane < 16){
      int w = wsum[lane];
      #pragma unroll
      for (int s=1;s<16;s<<=1){ int t = __shfl_up(w, s, 64); if (lane >= s) w += t; }
      wsum[lane] = w;
    }
    __syncthreads();
    int sbase = sbase_s;
    int wbase = sbase + (wave ? wsum[wave-1] : 0);
    int excl = wbase + inc - own;
    if (i0   < NN) offs[i0]   = excl;
    if (i0+1 < NN) offs[i0+1] = excl + v0;
    if (i0+2 < NN) offs[i0+2] = excl + v0+v1;
    if (i0+3 < NN) offs[i0+3] = excl + v0+v1+v2;
    __syncthreads();
    if (tid == 0) sbase_s = sbase + wsum[15];
    __syncthreads();
  }
  if (tid == 0) offs[NN] = sbase_s;
}

__global__ void k_fill(const int* __restrict__ src, const int* __restrict__ dst,
                       const int* __restrict__ offs, int* __restrict__ cur,
                       int* __restrict__ slist){
  int e = blockIdx.x*256 + threadIdx.x;
  if (e < NE){
    int d = dst[e];
    int p = atomicAdd(&cur[d], 1);
    slist[offs[d] + p] = src[e];
  }
}

// ---- K2a (MFMA): T[v][m] = gelu(Hb[v] @ WA^T) @ WB^T ----
__global__ __launch_bounds__(512) void k_node(const u16* __restrict__ Hb,
    const float* __restrict__ WA, const float* __restrict__ WB,
    float* __restrict__ T)
{
  extern __shared__ u16 was[];            // [128 h][136 k] bf16 padded
  const int LDW = 136;
  for (int idx4 = threadIdx.x*4; idx4 < 128*128; idx4 += 512*4){
    int h = idx4 >> 7, k = idx4 & 127;
    float4 v = *(const float4*)(WA + (size_t)h*128 + k);
    ushort2 p0, p1;
    p0.x = f2bfb(v.x); p0.y = f2bfb(v.y);
    p1.x = f2bfb(v.z); p1.y = f2bfb(v.w);
    *(ushort2*)&was[h*LDW + k]     = p0;
    *(ushort2*)&was[h*LDW + k + 2] = p1;
  }
  const int lane = threadIdx.x & 63;
  const int wave = threadIdx.x >> 6;
  const int lrow = lane & 15;
  const int kgrp = lane >> 4;
  float wbv[4][8];
  #pragma unroll
  for (int m = 0; m < 4; m++)
    #pragma unroll
    for (int nb = 0; nb < 8; nb++)
      wbv[m][nb] = WB[m*128 + nb*16 + lrow];
  __syncthreads();
  for (int tile = blockIdx.x*8 + wave; tile < NT; tile += gridDim.x*8){
    const u16* hr = Hb + (size_t)(tile*16 + lrow)*128 + kgrp*8;
    f32x4 acc[8];
    #pragma unroll
    for (int nb = 0; nb < 8; nb++) acc[nb] = (f32x4){0.f,0.f,0.f,0.f};
    #pragma unroll
    for (int kk = 0; kk < 4; kk++){
      short8 af = *(const short8*)(hr + kk*32);
      #pragma unroll
      for (int nb = 0; nb < 8; nb++){
        short8 bf = *(const short8*)&was[(nb*16 + lrow)*LDW + kk*32 + kgrp*8];
        acc[nb] = __builtin_amdgcn_mfma_f32_16x16x32_bf16(af, bf, acc[nb], 0, 0, 0);
      }
    }
    float part[4][4];   // [reg r][m]
    #pragma unroll
    for (int r = 0; r < 4; r++)
      #pragma unroll
      for (int m = 0; m < 4; m++) part[r][m] = 0.f;
    #pragma unroll
    for (int nb = 0; nb < 8; nb++){
      float g0 = geluf(acc[nb][0]), g1 = geluf(acc[nb][1]);
      float g2 = geluf(acc[nb][2]), g3 = geluf(acc[nb][3]);
      #pragma unroll
      for (int m = 0; m < 4; m++){
        float w = wbv[m][nb];
        part[0][m] += g0*w; part[1][m] += g1*w;
        part[2][m] += g2*w; part[3][m] += g3*w;
      }
    }
    #pragma unroll
    for (int s = 1; s < 16; s <<= 1)
      #pragma unroll
      for (int r = 0; r < 4; r++)
        #pragma unroll
        for (int m = 0; m < 4; m++)
          part[r][m] += __shfl_xor(part[r][m], s, 64);
    if (lrow == 0){
      #pragma unroll
      for (int r = 0; r < 4; r++){
        f32x4 tv = { part[r][0], part[r][1], part[r][2], part[r][3] };
        *(f32x4*)&T[(size_t)(tile*16 + kgrp*4 + r)*4] = tv;
      }
    }
  }
}

// ------- K2b: per-node aggregation, 8-edge unrolled gather -------
__global__ __launch_bounds__(256) void k_agg(const u16* __restrict__ Hb,
    const float* __restrict__ T, const int* __restrict__ offs,
    const int* __restrict__ slist, u16* __restrict__ GAb)
{
  const int lane = threadIdx.x & 63;
  const int wave = threadIdx.x >> 6;
  int v = blockIdx.x*4 + wave;
  if (v >= NN) return;
  int e0 = offs[v], e1 = offs[v+1];
  float ax0=0, ax1=0, ax2=0, ax3=0;   // h = 2*lane
  float ay0=0, ay1=0, ay2=0, ay3=0;   // h = 2*lane+1
  float s0=0, s1=0, s2=0, s3=0;
  int idx = e0;
  for (; idx + 8 <= e1; idx += 8){
    unsigned pk[8]; float4 tt[8];
    #pragma unroll
    for (int u = 0; u < 8; u++){
      int sn = slist[idx+u];
      pk[u] = *(const unsigned*)(Hb + (size_t)sn*128 + lane*2);
      tt[u] = *(const float4*)(T + (size_t)sn*4);
    }
    #pragma unroll
    for (int u = 0; u < 8; u++){
      float hx = bfb2f((u16)(pk[u] & 0xffffu));
      float hy = bfb2f((u16)(pk[u] >> 16));
      ax0 += hx*tt[u].x; ax1 += hx*tt[u].y; ax2 += hx*tt[u].z; ax3 += hx*tt[u].w;
      ay0 += hy*tt[u].x; ay1 += hy*tt[u].y; ay2 += hy*tt[u].z; ay3 += hy*tt[u].w;
      s0 += tt[u].x; s1 += tt[u].y; s2 += tt[u].z; s3 += tt[u].w;
    }
  }
  for (; idx + 4 <= e1; idx += 4){
    unsigned pk[4]; float4 tt[4];
    #pragma unroll
    for (int u = 0; u < 4; u++){
      int sn = slist[idx+u];
      pk[u] = *(const unsigned*)(Hb + (size_t)sn*128 + lane*2);
      tt[u] = *(const float4*)(T + (size_t)sn*4);
    }
    #pragma unroll
    for (int u = 0; u < 4; u++){
      float hx = bfb2f((u16)(pk[u] & 0xffffu));
      float hy = bfb2f((u16)(pk[u] >> 16));
      ax0 += hx*tt[u].x; ax1 += hx*tt[u].y; ax2 += hx*tt[u].z; ax3 += hx*tt[u].w;
      ay0 += hy*tt[u].x; ay1 += hy*tt[u].y; ay2 += hy*tt[u].z; ay3 += hy*tt[u].w;
      s0 += tt[u].x; s1 += tt[u].y; s2 += tt[u].z; s3 += tt[u].w;
    }
  }
  for (; idx < e1; idx++){
    int sn = slist[idx];
    unsigned pk = *(const unsigned*)(Hb + (size_t)sn*128 + lane*2);
    float hx = bfb2f((u16)(pk & 0xffffu));
    float hy = bfb2f((u16)(pk >> 16));
    float4 wt = *(const float4*)(T + (size_t)sn*4);
    ax0 += hx*wt.x; ax1 += hx*wt.y; ax2 += hx*wt.z; ax3 += hx*wt.w;
    ay0 += hy*wt.x; ay1 += hy*wt.y; ay2 += hy*wt.z; ay3 += hy*wt.w;
    s0 += wt.x; s1 += wt.y; s2 += wt.z; s3 += wt.w;
  }
  float inv = 1.0f / fmaxf((float)(e1 - e0), 1.0f);
  float ox = geluf(ax0)*s0 + geluf(ax1)*s1 + geluf(ax2)*s2 + geluf(ax3)*s3;
  float oy = geluf(ay0)*s0 + geluf(ay1)*s1 + geluf(ay2)*s2 + geluf(ay3)*s3;
  ushort2 res;
  res.x = f2bfb(geluf(ox * inv));
  res.y = f2bfb(geluf(oy * inv));
  *(ushort2*)(GAb + (size_t)v*128 + lane*2) = res;
}

// ------- K3 (MFMA, operand-swapped): out = [GAb, GHb] @ W2^T + b2 -------
// lane l holds out[tile*16+(l&15)][nb*16+kgrp*4+r] -> dwordx4 NT stores
__global__ __launch_bounds__(512) void k_ff2(const u16* __restrict__ GAb,
    const u16* __restrict__ GHb, const float* __restrict__ W2,
    const float* __restrict__ b2, float* __restrict__ out)
{
  extern __shared__ u16 w2s[];            // [128 o][264 k] bf16 padded
  const int LDW = 264;
  for (int idx4 = threadIdx.x*4; idx4 < 128*256; idx4 += 512*4){
    int o = idx4 >> 8, k = idx4 & 255;
    float4 v = *(const float4*)(W2 + (size_t)o*256 + k);
    ushort2 p0, p1;
    p0.x = f2bfb(v.x); p0.y = f2bfb(v.y);
    p1.x = f2bfb(v.z); p1.y = f2bfb(v.w);
    *(ushort2*)&w2s[o*LDW + k]     = p0;
    *(ushort2*)&w2s[o*LDW + k + 2] = p1;
  }
  __syncthreads();
  const int lane = threadIdx.x & 63;
  const int wave = threadIdx.x >> 6;
  const int lrow = lane & 15;
  const int kgrp = lane >> 4;
  float4 b2v[8];
  #pragma unroll
  for (int nb = 0; nb < 8; nb++) b2v[nb] = *(const float4*)(b2 + nb*16 + kgrp*4);
  for (int tile = blockIdx.x*8 + wave; tile < NT; tile += gridDim.x*8){
    const int row = tile*16 + lrow;
    const u16* aga = GAb + (size_t)row*128 + kgrp*8;
    const u16* agh = GHb + (size_t)row*128 + kgrp*8;
    f32x4 acc[8];
    #pragma unroll
    for (int nb = 0; nb < 8; nb++) acc[nb] = (f32x4){0.f,0.f,0.f,0.f};
    #pragma unroll
    for (int kk = 0; kk < 8; kk++){
      short8 af = (kk < 4) ? *(const short8*)(aga + kk*32)
                           : *(const short8*)(agh + (kk-4)*32);
      #pragma unroll
      for (int nb = 0; nb < 8; nb++){
        short8 bf = *(const short8*)&w2s[(nb*16 + lrow)*LDW + kk*32 + kgrp*8];
        acc[nb] = __builtin_amdgcn_mfma_f32_16x16x32_bf16(bf, af, acc[nb], 0, 0, 0);
      }
    }
    float* orp = out + (size_t)row*128 + kgrp*4;
    #pragma unroll
    for (int nb = 0; nb < 8; nb++){
      f32x4 o;
      o[0] = acc[nb][0] + b2v[nb].x;
      o[1] = acc[nb][1] + b2v[nb].y;
      o[2] = acc[nb][2] + b2v[nb].z;
      o[3] = acc[nb][3] + b2v[nb].w;
      __builtin_nontemporal_store(o, (f32x4*)(orp + nb*16));
    }
  }
}

extern "C" void kernel_launch(void* const* d_in, const int* in_sizes, int n_in,
                              void* d_out, int out_size, void* d_ws, size_t ws_size,
                              hipStream_t stream)
{
  (void)in_sizes; (void)n_in; (void)out_size; (void)ws_size;
  const float* X  = (const float*)d_in[0];
  const int*   ei = (const int*)d_in[1];
  const float* W1 = (const float*)d_in[2];
  const float* b1 = (const float*)d_in[3];
  const float* WA = (const float*)d_in[4];
  const float* WB = (const float*)d_in[5];
  const float* W2 = (const float*)d_in[6];
  const float* b2 = (const float*)d_in[7];
  float* out = (float*)d_out;
  const int* src = ei;
  const int* dst = ei + NE;

  char* p = (char*)d_ws;
  u16*   Hb   = (u16*)(p);                 // 12,800,000 B
  u16*   GHb  = (u16*)(p + 12800000);      // 12,800,000 B
  u16*   GAb  = (u16*)(p + 25600000);      // 12,800,000 B
  float* T    = (float*)(p + 38400000);    //    800,000 B
  int*   deg  = (int*)(p + 39200000);      //    200,192 B
  int*   cur  = (int*)(p + 39400192);      //    200,192 B
  int*   offs = (int*)(p + 39600384);      //    200,448 B
  int*   slist= (int*)(p + 39800832);      //  1,600,000 B  (total ~41.4 MB)

  (void)hipMemsetAsync(deg, 0, 400384, stream);  // zeroes deg + cur (contiguous)

  (void)hipFuncSetAttribute((const void*)k_ff2, hipFuncAttributeMaxDynamicSharedMemorySize, 128*264*2);

  k_ff1 <<<512, 512, 128*136*2, stream>>>(X, W1, b1, Hb, GHb);
  k_hist<<<(NE+255)/256, 256, 0, stream>>>(dst, deg);
  k_scan<<<1, 1024, 0, stream>>>(deg, offs);
  k_fill<<<(NE+255)/256, 256, 0, stream>>>(src, dst, offs, cur, slist);
  k_node<<<512, 512, 128*136*2, stream>>>(Hb, WA, WB, T);
  k_agg <<<(NN+3)/4, 256, 0, stream>>>(Hb, T, offs, slist, GAb);
  k_ff2 <<<512, 512, 128*264*2, stream>>>(GAb, GHb, W2, b2, out);
}

// Round 12
// 186.841 us; speedup vs baseline: 1.0382x; 1.0382x over previous
//
#include <hip/hip_runtime.h>
#include <hip/hip_bf16.h>

#define NN 50000
#define NE 400000
#define NT 3125   // NN/16 row tiles

typedef unsigned short u16;
typedef short short8 __attribute__((ext_vector_type(8)));
typedef float f32x4 __attribute__((ext_vector_type(4)));

__device__ __forceinline__ float geluf(float x){ return 0.5f*x*(1.0f+erff(x*0.70710678118654752440f)); }
__device__ __forceinline__ u16 f2bfb(float f){
  union { __hip_bfloat16 h; u16 u; } cv; cv.h = __float2bfloat16(f); return cv.u;
}
__device__ __forceinline__ float bfb2f(u16 u){ return __uint_as_float(((unsigned)u)<<16); }

// ---- K0: convert W1(16384) | WA(16384) | W2(32768) to bf16 once ----
__global__ __launch_bounds__(256) void k_cvt(const float* __restrict__ W1,
    const float* __restrict__ WA, const float* __restrict__ W2,
    u16* __restrict__ W1b, u16* __restrict__ WAb, u16* __restrict__ W2b)
{
  int i4 = (blockIdx.x*256 + threadIdx.x) * 4;   // grid 64 -> 65536 elements
  const float* srcp; u16* dstp; int off;
  if (i4 < 16384){ srcp = W1; dstp = W1b; off = i4; }
  else if (i4 < 32768){ srcp = WA; dstp = WAb; off = i4 - 16384; }
  else { srcp = W2; dstp = W2b; off = i4 - 32768; }
  float4 v = *(const float4*)(srcp + off);
  ushort4 o;
  o.x = f2bfb(v.x); o.y = f2bfb(v.y); o.z = f2bfb(v.z); o.w = f2bfb(v.w);
  *(ushort4*)(dstp + off) = o;
}

// ---- K1 (MFMA, operand-swapped): Hb/GHb; lane holds out[row=l&15][col=nb*16+kgrp*4+r]
__global__ __launch_bounds__(512) void k_ff1(const float* __restrict__ X,
    const u16* __restrict__ W1b, const float* __restrict__ b1,
    u16* __restrict__ Hb, u16* __restrict__ GHb)
{
  extern __shared__ u16 wls[];            // [128 c][136 k] bf16 padded
  const int LDW = 136;
  for (int idx8 = threadIdx.x*8; idx8 < 128*128; idx8 += 512*8){
    int c = idx8 >> 7, k = idx8 & 127;
    *(short8*)&wls[c*LDW + k] = *(const short8*)(W1b + idx8);
  }
  __syncthreads();
  const int lane = threadIdx.x & 63;
  const int wave = threadIdx.x >> 6;
  const int lrow = lane & 15;
  const int kgrp = lane >> 4;
  float4 b1v[8];
  #pragma unroll
  for (int nb = 0; nb < 8; nb++) b1v[nb] = *(const float4*)(b1 + nb*16 + kgrp*4);
  for (int tile = blockIdx.x*8 + wave; tile < NT; tile += gridDim.x*8){
    const float* xr = X + (size_t)(tile*16 + lrow)*128 + kgrp*8;
    f32x4 acc[8];
    #pragma unroll
    for (int nb = 0; nb < 8; nb++) acc[nb] = (f32x4){0.f,0.f,0.f,0.f};
    #pragma unroll
    for (int kk = 0; kk < 4; kk++){
      float4 xa = *(const float4*)(xr + kk*32);
      float4 xb = *(const float4*)(xr + kk*32 + 4);
      union { short8 v; u16 u[8]; } af;
      af.u[0]=f2bfb(xa.x); af.u[1]=f2bfb(xa.y); af.u[2]=f2bfb(xa.z); af.u[3]=f2bfb(xa.w);
      af.u[4]=f2bfb(xb.x); af.u[5]=f2bfb(xb.y); af.u[6]=f2bfb(xb.z); af.u[7]=f2bfb(xb.w);
      #pragma unroll
      for (int nb = 0; nb < 8; nb++){
        short8 bf = *(const short8*)&wls[(nb*16 + lrow)*LDW + kk*32 + kgrp*8];
        acc[nb] = __builtin_amdgcn_mfma_f32_16x16x32_bf16(bf, af.v, acc[nb], 0, 0, 0);
      }
    }
    const size_t rb = (size_t)(tile*16 + lrow)*128 + kgrp*4;
    #pragma unroll
    for (int nb = 0; nb < 8; nb++){
      ushort4 hp, gp;
      #pragma unroll
      for (int r = 0; r < 4; r++){
        float h = geluf(acc[nb][r] + b1v[nb][r]);
        ((u16*)&hp)[r] = f2bfb(h);
        ((u16*)&gp)[r] = f2bfb(geluf(h));
      }
      *(ushort4*)(Hb  + rb + nb*16) = hp;
      *(ushort4*)(GHb + rb + nb*16) = gp;
    }
  }
}

// ---------------- sort edges by dst: hist -> scan -> fill(src) ----------------
__global__ void k_hist(const int* __restrict__ dst, int* __restrict__ deg){
  int e = blockIdx.x*256 + threadIdx.x;
  if (e < NE) atomicAdd(&deg[dst[e]], 1);
}

__global__ __launch_bounds__(1024) void k_scan(const int* __restrict__ deg, int* __restrict__ offs){
  __shared__ int wsum[16];
  __shared__ int sbase_s;
  const int tid = threadIdx.x, lane = tid & 63, wave = tid >> 6;
  if (tid == 0) sbase_s = 0;
  __syncthreads();
  for (int base = 0; base < NN; base += 4096){
    int i0 = base + tid*4;
    int v0=0,v1=0,v2=0,v3=0;
    if (i0+3 < NN){ int4 v = *(const int4*)(deg+i0); v0=v.x;v1=v.y;v2=v.z;v3=v.w; }
    else {
      if (i0   < NN) v0 = deg[i0];
      if (i0+1 < NN) v1 = deg[i0+1];
      if (i0+2 < NN) v2 = deg[i0+2];
    }
    int own = v0+v1+v2+v3;
    int inc = own;
    #pragma unroll
    for (int s=1;s<64;s<<=1){ int t = __shfl_up(inc, s, 64); if (lane >= s) inc += t; }
    if (lane == 63) wsum[wave] = inc;
    __syncthreads();
    if (wave == 0 && lane < 16){
      int w = wsum[lane];
      #pragma unroll
      for (int s=1;s<16;s<<=1){ int t = __shfl_up(w, s, 64); if (lane >= s) w += t; }
      wsum[lane] = w;
    }
    __syncthreads();
    int sbase = sbase_s;
    int wbase = sbase + (wave ? wsum[wave-1] : 0);
    int excl = wbase + inc - own;
    if (i0   < NN) offs[i0]   = excl;
    if (i0+1 < NN) offs[i0+1] = excl + v0;
    if (i0+2 < NN) offs[i0+2] = excl + v0+v1;
    if (i0+3 < NN) offs[i0+3] = excl + v0+v1+v2;
    __syncthreads();
    if (tid == 0) sbase_s = sbase + wsum[15];
    __syncthreads();
  }
  if (tid == 0) offs[NN] = sbase_s;
}

__global__ void k_fill(const int* __restrict__ src, const int* __restrict__ dst,
                       const int* __restrict__ offs, int* __restrict__ cur,
                       int* __restrict__ slist){
  int e = blockIdx.x*256 + threadIdx.x;
  if (e < NE){
    int d = dst[e];
    int p = atomicAdd(&cur[d], 1);
    slist[offs[d] + p] = src[e];
  }
}

// ---- K2a (MFMA): T[v][m] = gelu(Hb[v] @ WA^T) @ WB^T ----
__global__ __launch_bounds__(512) void k_node(const u16* __restrict__ Hb,
    const u16* __restrict__ WAb, const float* __restrict__ WB,
    float* __restrict__ T)
{
  extern __shared__ u16 was[];            // [128 h][136 k] bf16 padded
  const int LDW = 136;
  for (int idx8 = threadIdx.x*8; idx8 < 128*128; idx8 += 512*8){
    int h = idx8 >> 7, k = idx8 & 127;
    *(short8*)&was[h*LDW + k] = *(const short8*)(WAb + idx8);
  }
  const int lane = threadIdx.x & 63;
  const int wave = threadIdx.x >> 6;
  const int lrow = lane & 15;
  const int kgrp = lane >> 4;
  float wbv[4][8];
  #pragma unroll
  for (int m = 0; m < 4; m++)
    #pragma unroll
    for (int nb = 0; nb < 8; nb++)
      wbv[m][nb] = WB[m*128 + nb*16 + lrow];
  __syncthreads();
  for (int tile = blockIdx.x*8 + wave; tile < NT; tile += gridDim.x*8){
    const u16* hr = Hb + (size_t)(tile*16 + lrow)*128 + kgrp*8;
    f32x4 acc[8];
    #pragma unroll
    for (int nb = 0; nb < 8; nb++) acc[nb] = (f32x4){0.f,0.f,0.f,0.f};
    #pragma unroll
    for (int kk = 0; kk < 4; kk++){
      short8 af = *(const short8*)(hr + kk*32);
      #pragma unroll
      for (int nb = 0; nb < 8; nb++){
        short8 bf = *(const short8*)&was[(nb*16 + lrow)*LDW + kk*32 + kgrp*8];
        acc[nb] = __builtin_amdgcn_mfma_f32_16x16x32_bf16(af, bf, acc[nb], 0, 0, 0);
      }
    }
    float part[4][4];   // [reg r][m]
    #pragma unroll
    for (int r = 0; r < 4; r++)
      #pragma unroll
      for (int m = 0; m < 4; m++) part[r][m] = 0.f;
    #pragma unroll
    for (int nb = 0; nb < 8; nb++){
      float g0 = geluf(acc[nb][0]), g1 = geluf(acc[nb][1]);
      float g2 = geluf(acc[nb][2]), g3 = geluf(acc[nb][3]);
      #pragma unroll
      for (int m = 0; m < 4; m++){
        float w = wbv[m][nb];
        part[0][m] += g0*w; part[1][m] += g1*w;
        part[2][m] += g2*w; part[3][m] += g3*w;
      }
    }
    #pragma unroll
    for (int s = 1; s < 16; s <<= 1)
      #pragma unroll
      for (int r = 0; r < 4; r++)
        #pragma unroll
        for (int m = 0; m < 4; m++)
          part[r][m] += __shfl_xor(part[r][m], s, 64);
    if (lrow == 0){
      #pragma unroll
      for (int r = 0; r < 4; r++){
        f32x4 tv = { part[r][0], part[r][1], part[r][2], part[r][3] };
        *(f32x4*)&T[(size_t)(tile*16 + kgrp*4 + r)*4] = tv;
      }
    }
  }
}

// ------- K2b: per-node aggregation, 8-edge unrolled gather -------
__global__ __launch_bounds__(256) void k_agg(const u16* __restrict__ Hb,
    const float* __restrict__ T, const int* __restrict__ offs,
    const int* __restrict__ slist, u16* __restrict__ GAb)
{
  const int lane = threadIdx.x & 63;
  const int wave = threadIdx.x >> 6;
  int v = blockIdx.x*4 + wave;
  if (v >= NN) return;
  int e0 = offs[v], e1 = offs[v+1];
  float ax0=0, ax1=0, ax2=0, ax3=0;   // h = 2*lane
  float ay0=0, ay1=0, ay2=0, ay3=0;   // h = 2*lane+1
  float s0=0, s1=0, s2=0, s3=0;
  int idx = e0;
  for (; idx + 8 <= e1; idx += 8){
    unsigned pk[8]; float4 tt[8];
    #pragma unroll
    for (int u = 0; u < 8; u++){
      int sn = slist[idx+u];
      pk[u] = *(const unsigned*)(Hb + (size_t)sn*128 + lane*2);
      tt[u] = *(const float4*)(T + (size_t)sn*4);
    }
    #pragma unroll
    for (int u = 0; u < 8; u++){
      float hx = bfb2f((u16)(pk[u] & 0xffffu));
      float hy = bfb2f((u16)(pk[u] >> 16));
      ax0 += hx*tt[u].x; ax1 += hx*tt[u].y; ax2 += hx*tt[u].z; ax3 += hx*tt[u].w;
      ay0 += hy*tt[u].x; ay1 += hy*tt[u].y; ay2 += hy*tt[u].z; ay3 += hy*tt[u].w;
      s0 += tt[u].x; s1 += tt[u].y; s2 += tt[u].z; s3 += tt[u].w;
    }
  }
  for (; idx + 4 <= e1; idx += 4){
    unsigned pk[4]; float4 tt[4];
    #pragma unroll
    for (int u = 0; u < 4; u++){
      int sn = slist[idx+u];
      pk[u] = *(const unsigned*)(Hb + (size_t)sn*128 + lane*2);
      tt[u] = *(const float4*)(T + (size_t)sn*4);
    }
    #pragma unroll
    for (int u = 0; u < 4; u++){
      float hx = bfb2f((u16)(pk[u] & 0xffffu));
      float hy = bfb2f((u16)(pk[u] >> 16));
      ax0 += hx*tt[u].x; ax1 += hx*tt[u].y; ax2 += hx*tt[u].z; ax3 += hx*tt[u].w;
      ay0 += hy*tt[u].x; ay1 += hy*tt[u].y; ay2 += hy*tt[u].z; ay3 += hy*tt[u].w;
      s0 += tt[u].x; s1 += tt[u].y; s2 += tt[u].z; s3 += tt[u].w;
    }
  }
  for (; idx < e1; idx++){
    int sn = slist[idx];
    unsigned pk = *(const unsigned*)(Hb + (size_t)sn*128 + lane*2);
    float hx = bfb2f((u16)(pk & 0xffffu));
    float hy = bfb2f((u16)(pk >> 16));
    float4 wt = *(const float4*)(T + (size_t)sn*4);
    ax0 += hx*wt.x; ax1 += hx*wt.y; ax2 += hx*wt.z; ax3 += hx*wt.w;
    ay0 += hy*wt.x; ay1 += hy*wt.y; ay2 += hy*wt.z; ay3 += hy*wt.w;
    s0 += wt.x; s1 += wt.y; s2 += wt.z; s3 += wt.w;
  }
  float inv = 1.0f / fmaxf((float)(e1 - e0), 1.0f);
  float ox = geluf(ax0)*s0 + geluf(ax1)*s1 + geluf(ax2)*s2 + geluf(ax3)*s3;
  float oy = geluf(ay0)*s0 + geluf(ay1)*s1 + geluf(ay2)*s2 + geluf(ay3)*s3;
  ushort2 res;
  res.x = f2bfb(geluf(ox * inv));
  res.y = f2bfb(geluf(oy * inv));
  *(ushort2*)(GAb + (size_t)v*128 + lane*2) = res;
}

// ------- K3 (MFMA, operand-swapped): out = [GAb, GHb] @ W2^T + b2 -------
// lane l holds out[tile*16+(l&15)][nb*16+kgrp*4+r] -> dwordx4 stores
__global__ __launch_bounds__(512) void k_ff2(const u16* __restrict__ GAb,
    const u16* __restrict__ GHb, const u16* __restrict__ W2b,
    const float* __restrict__ b2, float* __restrict__ out)
{
  extern __shared__ u16 w2s[];            // [128 o][264 k] bf16 padded
  const int LDW = 264;
  for (int idx8 = threadIdx.x*8; idx8 < 128*256; idx8 += 512*8){
    int o = idx8 >> 8, k = idx8 & 255;
    *(short8*)&w2s[o*LDW + k] = *(const short8*)(W2b + idx8);
  }
  __syncthreads();
  const int lane = threadIdx.x & 63;
  const int wave = threadIdx.x >> 6;
  const int lrow = lane & 15;
  const int kgrp = lane >> 4;
  float4 b2v[8];
  #pragma unroll
  for (int nb = 0; nb < 8; nb++) b2v[nb] = *(const float4*)(b2 + nb*16 + kgrp*4);
  for (int tile = blockIdx.x*8 + wave; tile < NT; tile += gridDim.x*8){
    const int row = tile*16 + lrow;
    const u16* aga = GAb + (size_t)row*128 + kgrp*8;
    const u16* agh = GHb + (size_t)row*128 + kgrp*8;
    f32x4 acc[8];
    #pragma unroll
    for (int nb = 0; nb < 8; nb++) acc[nb] = (f32x4){0.f,0.f,0.f,0.f};
    #pragma unroll
    for (int kk = 0; kk < 8; kk++){
      short8 af = (kk < 4) ? *(const short8*)(aga + kk*32)
                           : *(const short8*)(agh + (kk-4)*32);
      #pragma unroll
      for (int nb = 0; nb < 8; nb++){
        short8 bf = *(const short8*)&w2s[(nb*16 + lrow)*LDW + kk*32 + kgrp*8];
        acc[nb] = __builtin_amdgcn_mfma_f32_16x16x32_bf16(bf, af, acc[nb], 0, 0, 0);
      }
    }
    float* orp = out + (size_t)row*128 + kgrp*4;
    #pragma unroll
    for (int nb = 0; nb < 8; nb++){
      f32x4 o;
      o[0] = acc[nb][0] + b2v[nb].x;
      o[1] = acc[nb][1] + b2v[nb].y;
      o[2] = acc[nb][2] + b2v[nb].z;
      o[3] = acc[nb][3] + b2v[nb].w;
      *(f32x4*)(orp + nb*16) = o;
    }
  }
}

extern "C" void kernel_launch(void* const* d_in, const int* in_sizes, int n_in,
                              void* d_out, int out_size, void* d_ws, size_t ws_size,
                              hipStream_t stream)
{
  (void)in_sizes; (void)n_in; (void)out_size; (void)ws_size;
  const float* X  = (const float*)d_in[0];
  const int*   ei = (const int*)d_in[1];
  const float* W1 = (const float*)d_in[2];
  const float* b1 = (const float*)d_in[3];
  const float* WA = (const float*)d_in[4];
  const float* WB = (const float*)d_in[5];
  const float* W2 = (const float*)d_in[6];
  const float* b2 = (const float*)d_in[7];
  float* out = (float*)d_out;
  const int* src = ei;
  const int* dst = ei + NE;

  char* p = (char*)d_ws;
  u16*   Hb   = (u16*)(p);                 // 12,800,000 B
  u16*   GHb  = (u16*)(p + 12800000);      // 12,800,000 B
  u16*   GAb  = (u16*)(p + 25600000);      // 12,800,000 B
  float* T    = (float*)(p + 38400000);    //    800,000 B
  int*   deg  = (int*)(p + 39200000);      //    200,192 B
  int*   cur  = (int*)(p + 39400192);      //    200,192 B
  int*   offs = (int*)(p + 39600384);      //    200,448 B
  int*   slist= (int*)(p + 39800832);      //  1,600,000 B
  u16*   W1b  = (u16*)(p + 41400832);      //     32,768 B
  u16*   WAb  = (u16*)(p + 41433600);      //     32,768 B
  u16*   W2b  = (u16*)(p + 41466368);      //     65,536 B  (total ~41.5 MB)

  (void)hipMemsetAsync(deg, 0, 400384, stream);  // zeroes deg + cur (contiguous)

  (void)hipFuncSetAttribute((const void*)k_ff2, hipFuncAttributeMaxDynamicSharedMemorySize, 128*264*2);

  k_cvt <<<64, 256, 0, stream>>>(W1, WA, W2, W1b, WAb, W2b);
  k_ff1 <<<391, 512, 128*136*2, stream>>>(X, W1b, b1, Hb, GHb);
  k_hist<<<(NE+255)/256, 256, 0, stream>>>(dst, deg);
  k_scan<<<1, 1024, 0, stream>>>(deg, offs);
  k_fill<<<(NE+255)/256, 256, 0, stream>>>(src, dst, offs, cur, slist);
  k_node<<<391, 512, 128*136*2, stream>>>(Hb, WAb, WB, T);
  k_agg <<<(NN+3)/4, 256, 0, stream>>>(Hb, T, offs, slist, GAb);
  k_ff2 <<<391, 512, 128*264*2, stream>>>(GAb, GHb, W2b, b2, out);
}

// Round 13
// 171.509 us; speedup vs baseline: 1.1310x; 1.0894x over previous
//
#include <hip/hip_runtime.h>
#include <hip/hip_bf16.h>

#define NN 50000
#define NE 400000
#define NT 3125   // NN/16 row tiles

typedef unsigned short u16;
typedef short short8 __attribute__((ext_vector_type(8)));
typedef float f32x4 __attribute__((ext_vector_type(4)));

__device__ __forceinline__ float geluf(float x){ return 0.5f*x*(1.0f+erff(x*0.70710678118654752440f)); }
__device__ __forceinline__ u16 f2bfb(float f){
  union { __hip_bfloat16 h; u16 u; } cv; cv.h = __float2bfloat16(f); return cv.u;
}
__device__ __forceinline__ float bfb2f(u16 u){ return __uint_as_float(((unsigned)u)<<16); }

// ---- K0: cvt W1|WA|W2 to bf16 (blocks 0..63) + edge histogram (blocks 64+) ----
__global__ __launch_bounds__(256) void k_pre(const float* __restrict__ W1,
    const float* __restrict__ WA, const float* __restrict__ W2,
    u16* __restrict__ W1b, u16* __restrict__ WAb, u16* __restrict__ W2b,
    const int* __restrict__ dst, int* __restrict__ deg)
{
  if (blockIdx.x < 64){
    int i4 = (blockIdx.x*256 + threadIdx.x) * 4;
    const float* srcp; u16* dstp; int off;
    if (i4 < 16384){ srcp = W1; dstp = W1b; off = i4; }
    else if (i4 < 32768){ srcp = WA; dstp = WAb; off = i4 - 16384; }
    else { srcp = W2; dstp = W2b; off = i4 - 32768; }
    float4 v = *(const float4*)(srcp + off);
    ushort4 o;
    o.x = f2bfb(v.x); o.y = f2bfb(v.y); o.z = f2bfb(v.z); o.w = f2bfb(v.w);
    *(ushort4*)(dstp + off) = o;
  } else {
    int e = (blockIdx.x - 64)*256 + threadIdx.x;
    if (e < NE) atomicAdd(&deg[dst[e]], 1);
  }
}

// ---- K1 (MFMA, operand-swapped): Hb/GHb; lane holds out[row=l&15][col=nb*16+kgrp*4+r]
__global__ __launch_bounds__(512) void k_ff1(const float* __restrict__ X,
    const u16* __restrict__ W1b, const float* __restrict__ b1,
    u16* __restrict__ Hb, u16* __restrict__ GHb)
{
  extern __shared__ u16 wls[];            // [128 c][136 k] bf16 padded
  const int LDW = 136;
  for (int idx8 = threadIdx.x*8; idx8 < 128*128; idx8 += 512*8){
    int c = idx8 >> 7, k = idx8 & 127;
    *(short8*)&wls[c*LDW + k] = *(const short8*)(W1b + idx8);
  }
  __syncthreads();
  const int lane = threadIdx.x & 63;
  const int wave = threadIdx.x >> 6;
  const int lrow = lane & 15;
  const int kgrp = lane >> 4;
  float4 b1v[8];
  #pragma unroll
  for (int nb = 0; nb < 8; nb++) b1v[nb] = *(const float4*)(b1 + nb*16 + kgrp*4);
  for (int tile = blockIdx.x*8 + wave; tile < NT; tile += gridDim.x*8){
    const float* xr = X + (size_t)(tile*16 + lrow)*128 + kgrp*8;
    f32x4 acc[8];
    #pragma unroll
    for (int nb = 0; nb < 8; nb++) acc[nb] = (f32x4){0.f,0.f,0.f,0.f};
    #pragma unroll
    for (int kk = 0; kk < 4; kk++){
      float4 xa = *(const float4*)(xr + kk*32);
      float4 xb = *(const float4*)(xr + kk*32 + 4);
      union { short8 v; u16 u[8]; } af;
      af.u[0]=f2bfb(xa.x); af.u[1]=f2bfb(xa.y); af.u[2]=f2bfb(xa.z); af.u[3]=f2bfb(xa.w);
      af.u[4]=f2bfb(xb.x); af.u[5]=f2bfb(xb.y); af.u[6]=f2bfb(xb.z); af.u[7]=f2bfb(xb.w);
      #pragma unroll
      for (int nb = 0; nb < 8; nb++){
        short8 bf = *(const short8*)&wls[(nb*16 + lrow)*LDW + kk*32 + kgrp*8];
        acc[nb] = __builtin_amdgcn_mfma_f32_16x16x32_bf16(bf, af.v, acc[nb], 0, 0, 0);
      }
    }
    const size_t rb = (size_t)(tile*16 + lrow)*128 + kgrp*4;
    #pragma unroll
    for (int nb = 0; nb < 8; nb++){
      ushort4 hp, gp;
      #pragma unroll
      for (int r = 0; r < 4; r++){
        float h = geluf(acc[nb][r] + b1v[nb][r]);
        ((u16*)&hp)[r] = f2bfb(h);
        ((u16*)&gp)[r] = f2bfb(geluf(h));
      }
      *(ushort4*)(Hb  + rb + nb*16) = hp;
      *(ushort4*)(GHb + rb + nb*16) = gp;
    }
  }
}

__global__ __launch_bounds__(1024) void k_scan(const int* __restrict__ deg, int* __restrict__ offs){
  __shared__ int wsum[16];
  __shared__ int sbase_s;
  const int tid = threadIdx.x, lane = tid & 63, wave = tid >> 6;
  if (tid == 0) sbase_s = 0;
  __syncthreads();
  for (int base = 0; base < NN; base += 4096){
    int i0 = base + tid*4;
    int v0=0,v1=0,v2=0,v3=0;
    if (i0+3 < NN){ int4 v = *(const int4*)(deg+i0); v0=v.x;v1=v.y;v2=v.z;v3=v.w; }
    else {
      if (i0   < NN) v0 = deg[i0];
      if (i0+1 < NN) v1 = deg[i0+1];
      if (i0+2 < NN) v2 = deg[i0+2];
    }
    int own = v0+v1+v2+v3;
    int inc = own;
    #pragma unroll
    for (int s=1;s<64;s<<=1){ int t = __shfl_up(inc, s, 64); if (lane >= s) inc += t; }
    if (lane == 63) wsum[wave] = inc;
    __syncthreads();
    if (wave == 0 && lane < 16){
      int w = wsum[lane];
      #pragma unroll
      for (int s=1;s<16;s<<=1){ int t = __shfl_up(w, s, 64); if (lane >= s) w += t; }
      wsum[lane] = w;
    }
    __syncthreads();
    int sbase = sbase_s;
    int wbase = sbase + (wave ? wsum[wave-1] : 0);
    int excl = wbase + inc - own;
    if (i0   < NN) offs[i0]   = excl;
    if (i0+1 < NN) offs[i0+1] = excl + v0;
    if (i0+2 < NN) offs[i0+2] = excl + v0+v1;
    if (i0+3 < NN) offs[i0+3] = excl + v0+v1+v2;
    __syncthreads();
    if (tid == 0) sbase_s = sbase + wsum[15];
    __syncthreads();
  }
  if (tid == 0) offs[NN] = sbase_s;
}

__global__ void k_fill(const int* __restrict__ src, const int* __restrict__ dst,
                       const int* __restrict__ offs, int* __restrict__ cur,
                       int* __restrict__ slist){
  int e = blockIdx.x*256 + threadIdx.x;
  if (e < NE){
    int d = dst[e];
    int p = atomicAdd(&cur[d], 1);
    slist[offs[d] + p] = src[e];
  }
}

// ---- K2a (MFMA): T[v][m] = gelu(Hb[v] @ WA^T) @ WB^T ----
__global__ __launch_bounds__(512) void k_node(const u16* __restrict__ Hb,
    const u16* __restrict__ WAb, const float* __restrict__ WB,
    float* __restrict__ T)
{
  extern __shared__ u16 was[];            // [128 h][136 k] bf16 padded
  const int LDW = 136;
  for (int idx8 = threadIdx.x*8; idx8 < 128*128; idx8 += 512*8){
    int h = idx8 >> 7, k = idx8 & 127;
    *(short8*)&was[h*LDW + k] = *(const short8*)(WAb + idx8);
  }
  const int lane = threadIdx.x & 63;
  const int wave = threadIdx.x >> 6;
  const int lrow = lane & 15;
  const int kgrp = lane >> 4;
  float wbv[4][8];
  #pragma unroll
  for (int m = 0; m < 4; m++)
    #pragma unroll
    for (int nb = 0; nb < 8; nb++)
      wbv[m][nb] = WB[m*128 + nb*16 + lrow];
  __syncthreads();
  for (int tile = blockIdx.x*8 + wave; tile < NT; tile += gridDim.x*8){
    const u16* hr = Hb + (size_t)(tile*16 + lrow)*128 + kgrp*8;
    f32x4 acc[8];
    #pragma unroll
    for (int nb = 0; nb < 8; nb++) acc[nb] = (f32x4){0.f,0.f,0.f,0.f};
    #pragma unroll
    for (int kk = 0; kk < 4; kk++){
      short8 af = *(const short8*)(hr + kk*32);
      #pragma unroll
      for (int nb = 0; nb < 8; nb++){
        short8 bf = *(const short8*)&was[(nb*16 + lrow)*LDW + kk*32 + kgrp*8];
        acc[nb] = __builtin_amdgcn_mfma_f32_16x16x32_bf16(af, bf, acc[nb], 0, 0, 0);
      }
    }
    float part[4][4];   // [reg r][m]
    #pragma unroll
    for (int r = 0; r < 4; r++)
      #pragma unroll
      for (int m = 0; m < 4; m++) part[r][m] = 0.f;
    #pragma unroll
    for (int nb = 0; nb < 8; nb++){
      float g0 = geluf(acc[nb][0]), g1 = geluf(acc[nb][1]);
      float g2 = geluf(acc[nb][2]), g3 = geluf(acc[nb][3]);
      #pragma unroll
      for (int m = 0; m < 4; m++){
        float w = wbv[m][nb];
        part[0][m] += g0*w; part[1][m] += g1*w;
        part[2][m] += g2*w; part[3][m] += g3*w;
      }
    }
    #pragma unroll
    for (int s = 1; s < 16; s <<= 1)
      #pragma unroll
      for (int r = 0; r < 4; r++)
        #pragma unroll
        for (int m = 0; m < 4; m++)
          part[r][m] += __shfl_xor(part[r][m], s, 64);
    if (lrow == 0){
      #pragma unroll
      for (int r = 0; r < 4; r++){
        f32x4 tv = { part[r][0], part[r][1], part[r][2], part[r][3] };
        *(f32x4*)&T[(size_t)(tile*16 + kgrp*4 + r)*4] = tv;
      }
    }
  }
}

// ------- K2b: per-node aggregation; scalarized (SGPR) edge indices -------
__global__ __launch_bounds__(256) void k_agg(const u16* __restrict__ Hb,
    const float* __restrict__ T, const int* __restrict__ offs,
    const int* __restrict__ slist, u16* __restrict__ GAb)
{
  const int lane = threadIdx.x & 63;
  const int wave = threadIdx.x >> 6;
  const int vo = lane*2;
  for (int v = blockIdx.x*4 + wave; v < NN; v += gridDim.x*4){
    const int e0 = __builtin_amdgcn_readfirstlane(offs[v]);
    const int e1 = __builtin_amdgcn_readfirstlane(offs[v+1]);
    float ax0=0, ax1=0, ax2=0, ax3=0;   // h = 2*lane
    float ay0=0, ay1=0, ay2=0, ay3=0;   // h = 2*lane+1
    float s0=0, s1=0, s2=0, s3=0;
    int idx = e0;
    for (; idx + 8 <= e1; idx += 8){
      unsigned pk[8]; float4 tt[8];
      #pragma unroll
      for (int u = 0; u < 8; u++){
        int sn = slist[idx+u];                 // uniform addr -> s_load
        pk[u] = *(const unsigned*)(Hb + (size_t)sn*128 + vo);
        tt[u] = *(const float4*)(T + (size_t)sn*4);   // uniform -> s_load_dwordx4
      }
      #pragma unroll
      for (int u = 0; u < 8; u++){
        float hx = bfb2f((u16)(pk[u] & 0xffffu));
        float hy = bfb2f((u16)(pk[u] >> 16));
        ax0 += hx*tt[u].x; ax1 += hx*tt[u].y; ax2 += hx*tt[u].z; ax3 += hx*tt[u].w;
        ay0 += hy*tt[u].x; ay1 += hy*tt[u].y; ay2 += hy*tt[u].z; ay3 += hy*tt[u].w;
        s0 += tt[u].x; s1 += tt[u].y; s2 += tt[u].z; s3 += tt[u].w;
      }
    }
    for (; idx + 4 <= e1; idx += 4){
      unsigned pk[4]; float4 tt[4];
      #pragma unroll
      for (int u = 0; u < 4; u++){
        int sn = slist[idx+u];
        pk[u] = *(const unsigned*)(Hb + (size_t)sn*128 + vo);
        tt[u] = *(const float4*)(T + (size_t)sn*4);
      }
      #pragma unroll
      for (int u = 0; u < 4; u++){
        float hx = bfb2f((u16)(pk[u] & 0xffffu));
        float hy = bfb2f((u16)(pk[u] >> 16));
        ax0 += hx*tt[u].x; ax1 += hx*tt[u].y; ax2 += hx*tt[u].z; ax3 += hx*tt[u].w;
        ay0 += hy*tt[u].x; ay1 += hy*tt[u].y; ay2 += hy*tt[u].z; ay3 += hy*tt[u].w;
        s0 += tt[u].x; s1 += tt[u].y; s2 += tt[u].z; s3 += tt[u].w;
      }
    }
    for (; idx < e1; idx++){
      int sn = slist[idx];
      unsigned pk = *(const unsigned*)(Hb + (size_t)sn*128 + vo);
      float hx = bfb2f((u16)(pk & 0xffffu));
      float hy = bfb2f((u16)(pk >> 16));
      float4 wt = *(const float4*)(T + (size_t)sn*4);
      ax0 += hx*wt.x; ax1 += hx*wt.y; ax2 += hx*wt.z; ax3 += hx*wt.w;
      ay0 += hy*wt.x; ay1 += hy*wt.y; ay2 += hy*wt.z; ay3 += hy*wt.w;
      s0 += wt.x; s1 += wt.y; s2 += wt.z; s3 += wt.w;
    }
    float inv = 1.0f / fmaxf((float)(e1 - e0), 1.0f);
    float ox = geluf(ax0)*s0 + geluf(ax1)*s1 + geluf(ax2)*s2 + geluf(ax3)*s3;
    float oy = geluf(ay0)*s0 + geluf(ay1)*s1 + geluf(ay2)*s2 + geluf(ay3)*s3;
    ushort2 res;
    res.x = f2bfb(geluf(ox * inv));
    res.y = f2bfb(geluf(oy * inv));
    *(ushort2*)(GAb + (size_t)v*128 + vo) = res;
  }
}

// ------- K3 (MFMA, operand-swapped): out = [GAb, GHb] @ W2^T + b2 -------
__global__ __launch_bounds__(512) void k_ff2(const u16* __restrict__ GAb,
    const u16* __restrict__ GHb, const u16* __restrict__ W2b,
    const float* __restrict__ b2, float* __restrict__ out)
{
  extern __shared__ u16 w2s[];            // [128 o][264 k] bf16 padded
  const int LDW = 264;
  for (int idx8 = threadIdx.x*8; idx8 < 128*256; idx8 += 512*8){
    int o = idx8 >> 8, k = idx8 & 255;
    *(short8*)&w2s[o*LDW + k] = *(const short8*)(W2b + idx8);
  }
  __syncthreads();
  const int lane = threadIdx.x & 63;
  const int wave = threadIdx.x >> 6;
  const int lrow = lane & 15;
  const int kgrp = lane >> 4;
  float4 b2v[8];
  #pragma unroll
  for (int nb = 0; nb < 8; nb++) b2v[nb] = *(const float4*)(b2 + nb*16 + kgrp*4);
  for (int tile = blockIdx.x*8 + wave; tile < NT; tile += gridDim.x*8){
    const int row = tile*16 + lrow;
    const u16* aga = GAb + (size_t)row*128 + kgrp*8;
    const u16* agh = GHb + (size_t)row*128 + kgrp*8;
    f32x4 acc[8];
    #pragma unroll
    for (int nb = 0; nb < 8; nb++) acc[nb] = (f32x4){0.f,0.f,0.f,0.f};
    #pragma unroll
    for (int kk = 0; kk < 8; kk++){
      short8 af = (kk < 4) ? *(const short8*)(aga + kk*32)
                           : *(const short8*)(agh + (kk-4)*32);
      #pragma unroll
      for (int nb = 0; nb < 8; nb++){
        short8 bf = *(const short8*)&w2s[(nb*16 + lrow)*LDW + kk*32 + kgrp*8];
        acc[nb] = __builtin_amdgcn_mfma_f32_16x16x32_bf16(bf, af, acc[nb], 0, 0, 0);
      }
    }
    float* orp = out + (size_t)row*128 + kgrp*4;
    #pragma unroll
    for (int nb = 0; nb < 8; nb++){
      f32x4 o;
      o[0] = acc[nb][0] + b2v[nb].x;
      o[1] = acc[nb][1] + b2v[nb].y;
      o[2] = acc[nb][2] + b2v[nb].z;
      o[3] = acc[nb][3] + b2v[nb].w;
      *(f32x4*)(orp + nb*16) = o;
    }
  }
}

extern "C" void kernel_launch(void* const* d_in, const int* in_sizes, int n_in,
                              void* d_out, int out_size, void* d_ws, size_t ws_size,
                              hipStream_t stream)
{
  (void)in_sizes; (void)n_in; (void)out_size; (void)ws_size;
  const float* X  = (const float*)d_in[0];
  const int*   ei = (const int*)d_in[1];
  const float* W1 = (const float*)d_in[2];
  const float* b1 = (const float*)d_in[3];
  const float* WA = (const float*)d_in[4];
  const float* WB = (const float*)d_in[5];
  const float* W2 = (const float*)d_in[6];
  const float* b2 = (const float*)d_in[7];
  float* out = (float*)d_out;
  const int* src = ei;
  const int* dst = ei + NE;

  char* p = (char*)d_ws;
  u16*   Hb   = (u16*)(p);                 // 12,800,000 B
  u16*   GHb  = (u16*)(p + 12800000);      // 12,800,000 B
  u16*   GAb  = (u16*)(p + 25600000);      // 12,800,000 B
  float* T    = (float*)(p + 38400000);    //    800,000 B
  int*   deg  = (int*)(p + 39200000);      //    200,192 B
  int*   cur  = (int*)(p + 39400192);      //    200,192 B
  int*   offs = (int*)(p + 39600384);      //    200,448 B
  int*   slist= (int*)(p + 39800832);      //  1,600,000 B
  u16*   W1b  = (u16*)(p + 41400832);      //     32,768 B
  u16*   WAb  = (u16*)(p + 41433600);      //     32,768 B
  u16*   W2b  = (u16*)(p + 41466368);      //     65,536 B  (total ~41.5 MB)

  (void)hipMemsetAsync(deg, 0, 400384, stream);  // zeroes deg + cur (contiguous)

  (void)hipFuncSetAttribute((const void*)k_ff2, hipFuncAttributeMaxDynamicSharedMemorySize, 128*264*2);

  k_pre <<<64 + (NE+255)/256, 256, 0, stream>>>(W1, WA, W2, W1b, WAb, W2b, dst, deg);
  k_ff1 <<<391, 512, 128*136*2, stream>>>(X, W1b, b1, Hb, GHb);
  k_scan<<<1, 1024, 0, stream>>>(deg, offs);
  k_fill<<<(NE+255)/256, 256, 0, stream>>>(src, dst, offs, cur, slist);
  k_node<<<391, 512, 128*136*2, stream>>>(Hb, WAb, WB, T);
  k_agg <<<2048, 256, 0, stream>>>(Hb, T, offs, slist, GAb);
  k_ff2 <<<391, 512, 128*264*2, stream>>>(GAb, GHb, W2b, b2, out);
}